// Round 1
// baseline (1760.008 us; speedup 1.0000x reference)
//
#include <hip/hip_runtime.h>

#define TSTEPS 32
#define BATCH  128
#define HID    1024
#define HH     512
#define VOUT   32000

typedef short bf16x8 __attribute__((ext_vector_type(8)));
typedef float f32x4  __attribute__((ext_vector_type(4)));

__device__ __forceinline__ unsigned short f2bf(float f) {
    unsigned int u = __float_as_uint(f);
    u += 0x7fffu + ((u >> 16) & 1u);   // RNE
    return (unsigned short)(u >> 16);
}

__device__ __forceinline__ void gload16(const void* g, void* l) {
    __builtin_amdgcn_global_load_lds(
        (const __attribute__((address_space(1))) void*)g,
        (__attribute__((address_space(3))) void*)l,
        16, 0, 0);
}

// ---------------- fp32 -> bf16 conversion (optional fused relu) ------------
__global__ void convert_bf16(const float* __restrict__ src,
                             unsigned short* __restrict__ dst,
                             int n4, int do_relu) {
    int stride = gridDim.x * blockDim.x;
    for (int i = blockIdx.x * blockDim.x + threadIdx.x; i < n4; i += stride) {
        float4 v = ((const float4*)src)[i];
        if (do_relu) {
            v.x = fmaxf(v.x, 0.f); v.y = fmaxf(v.y, 0.f);
            v.z = fmaxf(v.z, 0.f); v.w = fmaxf(v.w, 0.f);
        }
        ushort4 o;
        o.x = f2bf(v.x); o.y = f2bf(v.y); o.z = f2bf(v.z); o.w = f2bf(v.w);
        ((ushort4*)dst)[i] = o;
    }
}

// ---------------------------------------------------------------------------
// C[m][n] = sum_k A[m][k]*B[n][k] + bias[n]   (A bf16 [M][K], B row-major [N][K])
// EPI==0: Cout[m*N+n] = v (fp32 logits)
// EPI==1: enc epilogue -> hstate/hbf for BOTH directions
// PREB==1: B is pre-converted bf16; PREB==0: B fp32, reg-staged + converted.
// m97 structure: 128x128 tile, BK=32, double-buffered LDS, global_load_lds x16.
// ---------------------------------------------------------------------------
template<int EPI, int PREB>
__global__ void gemm128(const unsigned short* __restrict__ A,
                        const void* __restrict__ Bv,
                        const float* __restrict__ bias,
                        float* __restrict__ Cout,
                        float* __restrict__ hstate0,
                        unsigned short* __restrict__ hbf0,
                        int K, int N, int mtiles) {
    __shared__ __attribute__((aligned(16))) unsigned short As[2][128 * 32];
    __shared__ __attribute__((aligned(16))) unsigned short Bs[2][128 * 32];

    int nwg = gridDim.x;
    int wg = blockIdx.x;
    if ((nwg & 7) == 0) {                 // bijective XCD swizzle
        int q = nwg >> 3;
        wg = (wg & 7) * q + (wg >> 3);
    }
    int bx = wg / mtiles;                 // n-tile (consecutive wgs share B panel)
    int by = wg - bx * mtiles;            // m-tile
    int m0 = by * 128, n0 = bx * 128;

    int tid = threadIdx.x;
    int wid = tid >> 6, lane = tid & 63;
    int wm = wid >> 1, wn = wid & 1;
    int l15 = lane & 15, l4 = lane >> 4;

    f32x4 acc[4][4] = {};
    float4 breg[4];

    auto stageA = [&](int ks, int buf) {
        int k0 = ks * 32;
#pragma unroll
        for (int i = 0; i < 2; ++i) {
            int o16 = i * 256 + tid;      // 16B slot in 8KB tile
            int row = o16 >> 2;           // 64B per row
            int kk = (o16 & 3) * 8;
            gload16(A + (size_t)(m0 + row) * K + k0 + kk,
                    (char*)&As[buf][0] + i * 4096 + wid * 1024);
        }
    };
    auto stageBpre = [&](int ks, int buf) {
        const unsigned short* Bb = (const unsigned short*)Bv;
        int k0 = ks * 32;
#pragma unroll
        for (int i = 0; i < 2; ++i) {
            int o16 = i * 256 + tid;
            int row = o16 >> 2;
            int kk = (o16 & 3) * 8;
            gload16(Bb + (size_t)(n0 + row) * K + k0 + kk,
                    (char*)&Bs[buf][0] + i * 4096 + wid * 1024);
        }
    };
    auto loadBf32 = [&](int ks) {         // issue-early (T14): loads into regs
        const float* Bf = (const float*)Bv;
        int k0 = ks * 32;
#pragma unroll
        for (int i = 0; i < 4; ++i) {
            int o4 = i * 256 + tid;       // float4 slot in 16KB fp32 tile
            int row = o4 >> 3;
            int kk = (o4 & 7) * 4;
            breg[i] = *(const float4*)(Bf + (size_t)(n0 + row) * K + k0 + kk);
        }
    };
    auto writeBf32 = [&](int buf) {       // write-late: cvt + ds_write after MFMA
#pragma unroll
        for (int i = 0; i < 4; ++i) {
            int o4 = i * 256 + tid;
            int row = o4 >> 3;
            int kk = (o4 & 7) * 4;
            ushort4 o;
            o.x = f2bf(breg[i].x); o.y = f2bf(breg[i].y);
            o.z = f2bf(breg[i].z); o.w = f2bf(breg[i].w);
            *(ushort4*)((char*)&Bs[buf][0] + row * 64 + kk * 2) = o;
        }
    };
    auto compute = [&](int buf) {
        bf16x8 af[4], bfr[4];
#pragma unroll
        for (int mi = 0; mi < 4; ++mi) {
            int row = wm * 64 + mi * 16 + l15;
            af[mi] = *(const bf16x8*)((const char*)&As[buf][0] + row * 64 + l4 * 16);
        }
#pragma unroll
        for (int ni = 0; ni < 4; ++ni) {
            int row = wn * 64 + ni * 16 + l15;
            bfr[ni] = *(const bf16x8*)((const char*)&Bs[buf][0] + row * 64 + l4 * 16);
        }
#pragma unroll
        for (int mi = 0; mi < 4; ++mi)
#pragma unroll
            for (int ni = 0; ni < 4; ++ni)
                acc[mi][ni] = __builtin_amdgcn_mfma_f32_16x16x32_bf16(
                    af[mi], bfr[ni], acc[mi][ni], 0, 0, 0);
    };

    int NK = K >> 5;
    stageA(0, 0);
    if (PREB) stageBpre(0, 0);
    else { loadBf32(0); writeBf32(0); }
    __syncthreads();
    for (int ks = 0; ks < NK; ++ks) {
        int cur = ks & 1;
        int nxt = cur ^ 1;
        if (ks + 1 < NK) {
            stageA(ks + 1, nxt);
            if (PREB) stageBpre(ks + 1, nxt);
            else loadBf32(ks + 1);
        }
        compute(cur);
        if (!PREB && ks + 1 < NK) writeBf32(nxt);
        __syncthreads();
    }

    // epilogue: C/D layout col = lane&15, row = (lane>>4)*4 + reg  [m89-verified]
#pragma unroll
    for (int ni = 0; ni < 4; ++ni) {
        int n = n0 + wn * 64 + ni * 16 + l15;
        float bv = bias[n];
#pragma unroll
        for (int mi = 0; mi < 4; ++mi) {
#pragma unroll
            for (int r = 0; r < 4; ++r) {
                int m = m0 + wm * 64 + mi * 16 + l4 * 4 + r;
                float v = acc[mi][ni][r] + bv;
                if (EPI == 0) {
                    Cout[(size_t)m * N + n] = v;
                } else {
                    hstate0[m * HH + n] = v;
                    hstate0[BATCH * HH + m * HH + n] = v;
                    unsigned short hb = f2bf(v);
                    hbf0[m * HH + n] = hb;
                    hbf0[BATCH * HH + m * HH + n] = hb;
                }
            }
        }
    }
}

// ---------------------------------------------------------------------------
// One GRU time step, both directions. 32 wgs: dir = wg>>4, j0 = (wg&15)*32.
// Each wg computes gh = h @ W_hh[j-triple rows]^T via MFMA, then fuses the
// gate nonlinearities (all biases, r/z/n, state update) in the epilogue.
// ---------------------------------------------------------------------------
__global__ void gru_step(const unsigned short* __restrict__ whh,  // [2][1536][512] bf16
                         const unsigned short* __restrict__ hbc,  // [2][128][512] bf16
                         const float* __restrict__ hsc,           // [2][128][512] fp32
                         const float* __restrict__ bih_f,
                         const float* __restrict__ bhh_f,
                         const float* __restrict__ bih_r,
                         const float* __restrict__ bhh_r,
                         float* __restrict__ hsn,
                         unsigned short* __restrict__ hbn,
                         unsigned short* __restrict__ hcat,       // [32][128][1024] bf16
                         int tstep) {
    __shared__ __attribute__((aligned(16))) unsigned short Ah[128 * 64];
    __shared__ __attribute__((aligned(16))) unsigned short Bh[96 * 64];
    int dir = blockIdx.x >> 4;
    int j0 = (blockIdx.x & 15) * 32;
    int tid = threadIdx.x;
    int wid = tid >> 6, lane = tid & 63;
    int l15 = lane & 15, l4 = lane >> 4;
    const float* bih = dir ? bih_r : bih_f;
    const float* bhh = dir ? bhh_r : bhh_f;
    const size_t hoff = (size_t)dir * (BATCH * HH);
    const unsigned short* wbase = whh + (size_t)dir * (3 * HH * HH);

    f32x4 acc[2][6] = {};

    for (int ks = 0; ks < 8; ++ks) {
        if (ks) __syncthreads();          // LDS reuse guard
        int k0 = ks * 64;
#pragma unroll
        for (int i = 0; i < 4; ++i) {     // A: h chunk [128][64]
            int o16 = i * 256 + tid;
            int row = o16 >> 3;           // 128B rows
            int kk = (o16 & 7) * 8;
            gload16(hbc + hoff + (size_t)row * HH + k0 + kk,
                    (char*)Ah + i * 4096 + wid * 1024);
        }
#pragma unroll
        for (int i = 0; i < 3; ++i) {     // B: W rows {j0..+32, 512+j0.., 1024+j0..}
            int o16 = i * 256 + tid;
            int row = o16 >> 3;
            int kk = (o16 & 7) * 8;
            int wrow = (row < 32) ? (j0 + row)
                     : (row < 64) ? (HH + j0 + row - 32)
                                  : (2 * HH + j0 + row - 64);
            gload16(wbase + (size_t)wrow * HH + k0 + kk,
                    (char*)Bh + i * 4096 + wid * 1024);
        }
        __syncthreads();
#pragma unroll
        for (int kk = 0; kk < 2; ++kk) {
            bf16x8 a[2], b[6];
#pragma unroll
            for (int mi = 0; mi < 2; ++mi)
                a[mi] = *(const bf16x8*)((const char*)Ah +
                        (wid * 32 + mi * 16 + l15) * 128 + kk * 64 + l4 * 16);
#pragma unroll
            for (int ni = 0; ni < 6; ++ni)
                b[ni] = *(const bf16x8*)((const char*)Bh +
                        (ni * 16 + l15) * 128 + kk * 64 + l4 * 16);
#pragma unroll
            for (int mi = 0; mi < 2; ++mi)
#pragma unroll
                for (int ni = 0; ni < 6; ++ni)
                    acc[mi][ni] = __builtin_amdgcn_mfma_f32_16x16x32_bf16(
                        a[mi], b[ni], acc[mi][ni], 0, 0, 0);
        }
    }

#pragma unroll
    for (int p = 0; p < 2; ++p) {
        int j = j0 + p * 16 + l15;
        float bir = bih[j], biz = bih[HH + j], bin = bih[2 * HH + j];
        float bhr = bhh[j], bhz = bhh[HH + j], bhn = bhh[2 * HH + j];
#pragma unroll
        for (int mi = 0; mi < 2; ++mi) {
#pragma unroll
            for (int r = 0; r < 4; ++r) {
                int b = wid * 32 + mi * 16 + l4 * 4 + r;
                float ghr = acc[mi][p][r];
                float ghz = acc[mi][2 + p][r];
                float ghn = acc[mi][4 + p][r];
                float rr = 1.f / (1.f + __expf(-(bir + ghr + bhr)));
                float zz = 1.f / (1.f + __expf(-(biz + ghz + bhz)));
                float nx = bin + rr * (ghn + bhn);
                float nn = 1.f - 2.f / (__expf(2.f * nx) + 1.f);   // tanh
                float ho = hsc[hoff + (size_t)b * HH + j];
                float hv = (1.f - zz) * nn + zz * ho;
                hsn[hoff + (size_t)b * HH + j] = hv;
                unsigned short hb = f2bf(hv);
                hbn[hoff + (size_t)b * HH + j] = hb;
                int trow = dir ? (TSTEPS - 1 - tstep) : tstep;
                hcat[((size_t)trow * BATCH + b) * HID + dir * HH + j] = hb;
            }
        }
    }
}

// ---------------------------------------------------------------------------
__global__ void lse_kernel(const float* __restrict__ logits, float* __restrict__ lse) {
    int row = blockIdx.x;
    const float* base = logits + (size_t)row * VOUT;
    float m = -1e30f, s = 0.f;
    for (int v = threadIdx.x; v < VOUT; v += 256) {
        float x = base[v];
        if (x > m) { s = s * __expf(m - x) + 1.f; m = x; }
        else s += __expf(x - m);
    }
#pragma unroll
    for (int off = 1; off < 64; off <<= 1) {
        float m2 = __shfl_xor(m, off);
        float s2 = __shfl_xor(s, off);
        float nm = fmaxf(m, m2);
        s = s * __expf(m - nm) + s2 * __expf(m2 - nm);
        m = nm;
    }
    __shared__ float sm[4], ss[4];
    int wid = threadIdx.x >> 6;
    if ((threadIdx.x & 63) == 0) { sm[wid] = m; ss[wid] = s; }
    __syncthreads();
    if (threadIdx.x == 0) {
        float M = sm[0], S = ss[0];
        for (int w = 1; w < 4; ++w) {
            float nm = fmaxf(M, sm[w]);
            S = S * __expf(M - nm) + ss[w] * __expf(sm[w] - nm);
            M = nm;
        }
        lse[row] = M + __logf(S);
    }
}

__global__ void sub_kernel(float* __restrict__ out, const float* __restrict__ lse) {
    size_t stride = (size_t)gridDim.x * blockDim.x;
    size_t n4 = (size_t)TSTEPS * BATCH * VOUT / 4;
    for (size_t i = (size_t)blockIdx.x * blockDim.x + threadIdx.x; i < n4; i += stride) {
        float4 v = ((float4*)out)[i];
        int row = (int)(i * 4 / VOUT);       // 32000 % 4 == 0: row uniform per float4
        float l = lse[row];
        v.x -= l; v.y -= l; v.z -= l; v.w -= l;
        ((float4*)out)[i] = v;
    }
}

// ---------------------------------------------------------------------------
extern "C" void kernel_launch(void* const* d_in, const int* in_sizes, int n_in,
                              void* d_out, int out_size, void* d_ws, size_t ws_size,
                              hipStream_t stream) {
    const float* hidden = (const float*)d_in[0];
    const float* W_sq   = (const float*)d_in[1];
    const float* b_sq   = (const float*)d_in[2];
    const float* W_hh_f = (const float*)d_in[3];
    const float* b_ih_f = (const float*)d_in[4];
    const float* b_hh_f = (const float*)d_in[5];
    const float* W_hh_r = (const float*)d_in[6];
    const float* b_ih_r = (const float*)d_in[7];
    const float* b_hh_r = (const float*)d_in[8];
    const float* W_out  = (const float*)d_in[9];
    const float* b_out  = (const float*)d_in[10];
    float* out = (float*)d_out;

    // workspace layout (bytes)
    char* ws = (char*)d_ws;
    unsigned short* hcat  = (unsigned short*)(ws);             // 8,388,608
    unsigned short* whh   = (unsigned short*)(ws + 8388608);   // 3,145,728
    unsigned short* wsq   = (unsigned short*)(ws + 11534336);  // 1,048,576
    unsigned short* hrelu = (unsigned short*)(ws + 12582912);  //   262,144
    float* hst0 = (float*)(ws + 12845056);                     //   524,288
    float* hst1 = (float*)(ws + 13369344);                     //   524,288
    unsigned short* hbf0 = (unsigned short*)(ws + 13893632);   //   262,144
    unsigned short* hbf1 = (unsigned short*)(ws + 14155776);   //   262,144
    float* lse  = (float*)(ws + 14417920);                     //    16,384
    unsigned short* woutb = (unsigned short*)(ws + 14434304);  // 65,536,000
    bool preb = ws_size >= (size_t)14434304 + 65536000;

    auto cg = [](int n4) { int g = (n4 + 255) / 256; return g > 2048 ? 2048 : g; };

    convert_bf16<<<cg(196608), 256, 0, stream>>>(W_hh_f, whh, 196608, 0);
    convert_bf16<<<cg(196608), 256, 0, stream>>>(W_hh_r, whh + 786432, 196608, 0);
    convert_bf16<<<cg(131072), 256, 0, stream>>>(W_sq, wsq, 131072, 0);
    convert_bf16<<<cg(32768), 256, 0, stream>>>(hidden, hrelu, 32768, 1);
    if (preb)
        convert_bf16<<<2048, 256, 0, stream>>>(W_out, woutb, 8192000, 0);

    // enc = relu(hidden) @ W_sq^T + b_sq  -> initial GRU state (both dirs)
    gemm128<1, 1><<<4, 256, 0, stream>>>(hrelu, wsq, b_sq, nullptr, hst0, hbf0,
                                         HID, HH, 1);

    float* hsc = hst0; float* hsn = hst1;
    unsigned short* hbc = hbf0; unsigned short* hbn = hbf1;
    for (int t = 0; t < TSTEPS; ++t) {
        gru_step<<<32, 256, 0, stream>>>(whh, hbc, hsc, b_ih_f, b_hh_f,
                                         b_ih_r, b_hh_r, hsn, hbn, hcat, t);
        float* tf = hsc; hsc = hsn; hsn = tf;
        unsigned short* tb = hbc; hbc = hbn; hbn = tb;
    }

    // logits = hcat @ W_out^T + b_out  -> d_out
    if (preb)
        gemm128<0, 1><<<8000, 256, 0, stream>>>(hcat, woutb, b_out, out,
                                                nullptr, nullptr, HID, VOUT, 32);
    else
        gemm128<0, 0><<<8000, 256, 0, stream>>>(hcat, (const void*)W_out, b_out, out,
                                                nullptr, nullptr, HID, VOUT, 32);

    // log_softmax over V
    lse_kernel<<<4096, 256, 0, stream>>>(out, lse);
    sub_kernel<<<2048, 256, 0, stream>>>(out, lse);
}